// Round 12
// baseline (1093.925 us; speedup 1.0000x reference)
//
#include <hip/hip_runtime.h>
#include <hip/hip_bf16.h>
#include <cstdint>
#include <cstddef>

// Problem constants
constexpr int NB = 32;     // batch
constexpr int NH = 16;     // heads
constexpr int NS = 8192;   // seq len
constexpr int NK = 2048;   // top-k
constexpr int NL = 512;    // latent dim
constexpr int NDR = 64;    // rope dim
constexpr int NDV = 128;   // v head dim
constexpr int NDM = 2048;  // model dim
constexpr int NDN = 128;   // nope dim
constexpr float SCALE = 0.07216878364870322f; // 1/sqrt(192)

constexpr int NSPLIT = 32;      // k-splits
constexpr int KC = NK / NSPLIT; // 64 k per block
constexpr int ND = NL + NDR;    // 576 staged dims
constexpr int NSUB_D = ND / 16; // 36 subtiles per 4-row group
constexpr int NS2 = 64;         // k-chunks for final GEMM (32 n each)

// DIAGNOSTIC: surface k_attn and k_combine in rocprof top-5 with counters.
// t_combine = (dur - 94 - 15*27) / 95 ; both rows readable directly.
constexpr int REP_A = 16;
constexpr int REP_C = 96;

typedef __attribute__((ext_vector_type(8))) short sh8;
typedef __attribute__((ext_vector_type(4))) float f32x4;

__device__ __forceinline__ short bf16c(float f) {
  union { float f; uint32_t u; } v; v.f = f;
  uint32_t r = v.u + 0x7fffu + ((v.u >> 16) & 1u);
  return (short)(r >> 16);
}

__device__ __forceinline__ float bf2f(short s) {
  union { uint32_t u; float f; } v; v.u = ((uint32_t)(uint16_t)s) << 16;
  return v.f;
}

__device__ __forceinline__ sh8 pack_bf8(float4 a, float4 b) {
  sh8 f;
  f[0] = bf16c(a.x); f[1] = bf16c(a.y); f[2] = bf16c(a.z); f[3] = bf16c(a.w);
  f[4] = bf16c(b.x); f[5] = bf16c(b.y); f[6] = bf16c(b.z); f[7] = bf16c(b.w);
  return f;
}

// ---------------- Kernel 1: qle via LDS-staged coalesced tiles
__global__ __launch_bounds__(256)
void k_qprep(const float* __restrict__ qn,
             const float* __restrict__ qpe,
             const float* __restrict__ wuk,
             short* __restrict__ qle) {
  const int h  = blockIdx.x & 15;
  const int lc = blockIdx.x >> 4;
  const int l0 = lc * 32;
  const int t  = threadIdx.x;
  __shared__ float wlds[32 * 136];
  __shared__ float qlds[32 * 136];

  #pragma unroll
  for (int j = 0; j < 4; ++j) {
    int idx = t + j * 256;
    int li  = idx >> 5;
    int d4  = (idx & 31) * 4;
    *(float4*)&wlds[li * 136 + d4] =
        *(const float4*)&wuk[((size_t)(l0 + li) * NH + h) * NDN + d4];
    *(float4*)&qlds[li * 136 + d4] =
        *(const float4*)&qn[((size_t)li * NH + h) * NDN + d4];
  }
  __syncthreads();

  const int b = t >> 3;
  #pragma unroll
  for (int j = 0; j < 4; ++j) {
    int li = (t & 7) + j * 8;
    float acc = 0.f;
    #pragma unroll
    for (int d4 = 0; d4 < NDN; d4 += 4) {
      float4 wv = *(float4*)&wlds[li * 136 + d4];
      float4 qv = *(float4*)&qlds[b * 136 + d4];
      acc += wv.x * qv.x + wv.y * qv.y + wv.z * qv.z + wv.w * qv.w;
    }
    qle[((size_t)b * NH + h) * ND + l0 + li] = bf16c(acc);
  }
  if (lc == 0) {
    #pragma unroll
    for (int j = 0; j < 8; ++j) {
      int i = t + j * 256;
      int bb = i >> 6, dr = i & 63;
      qle[((size_t)bb * NH + h) * ND + NL + dr] =
          bf16c(qpe[((size_t)bb * NH + h) * NDR + dr]);
    }
  }
}

// ---------------- Kernel 2: MFMA flash attention partial — DIAGNOSTIC REP_A x
__global__ __launch_bounds__(256, 2)
void k_attn(const float* __restrict__ kvc,
            const float* __restrict__ kpe,
            const int*   __restrict__ topk,
            const short* __restrict__ qle,
            float* __restrict__ pm,
            float* __restrict__ psum,
            unsigned short* __restrict__ po) {
  const int sp = blockIdx.x;     // 0..NSPLIT-1
  const int b  = blockIdx.y;     // 0..NB-1
  const int t  = threadIdx.x;
  const int w  = t >> 6;         // wave 0..3
  const int lane = t & 63;
  const int lg = lane >> 4;      // lane group 0..3
  const int ln = lane & 15;

  __shared__ __align__(16) short kvs[(KC / 4) * NSUB_D * 64];   // 73728 B
  __shared__ __align__(16) short plds[NH * 72];
  __shared__ float mlds[4 * NH];
  __shared__ float slds[4 * NH];

  for (int rep = 0; rep < REP_A; ++rep) {
    int zero;
    asm volatile("v_mov_b32 %0, 0" : "=v"(zero));
    const float* kvc_r = kvc + zero;
    const float* kpe_r = kpe + zero;
    const short* qle_r = qle + zero;
    const int*   tk_r  = topk + zero;

    // ---- gather-stage kv tile (64 rows x 576) as bf16 into subtiled LDS
    {
      const int r = t >> 2, c8 = t & 3;
      int idx = tk_r[(size_t)b * NK + sp * KC + r];
      int id = idx < 0 ? 0 : (idx >= NS ? NS - 1 : idx);
      const float* rowc = kvc_r + ((size_t)b * NS + id) * NL;
      const float* rowp = kpe_r + ((size_t)b * NS + id) * NDR;
      #pragma unroll
      for (int g = 0; g < 3; ++g) {
        float4 va[6], vb[6];
        #pragma unroll
        for (int i = 0; i < 6; ++i) {
          int d0 = c8 * 8 + (g * 6 + i) * 32;
          const float* src = (d0 < NL) ? (rowc + d0) : (rowp + (d0 - NL));
          va[i] = *(const float4*)src;
          vb[i] = *(const float4*)(src + 4);
        }
        #pragma unroll
        for (int i = 0; i < 6; ++i) {
          int d0 = c8 * 8 + (g * 6 + i) * 32;
          int s = (r >> 2) * NSUB_D + (d0 >> 4);
          *(sh8*)&kvs[s * 64 + (r & 3) * 16 + (d0 & 15)] = pack_bf8(va[i], vb[i]);
        }
      }
    }
    __syncthreads();

    // ---- QK^T
    f32x4 accs = {0.f, 0.f, 0.f, 0.f};
    {
      const short* qrow = qle_r + ((size_t)b * NH + ln) * ND;
      int k = w * 16 + ln;
      int kbase = (k >> 2) * NSUB_D * 64 + (k & 3) * 16;
      #pragma unroll
      for (int kk = 0; kk < 18; ++kk) {
        int d0 = kk * 32 + lg * 8;
        sh8 qv = *(const sh8*)&qrow[d0];
        sh8 bfr = *(const sh8*)&kvs[kbase + (d0 >> 4) * 64 + (d0 & 15)];
        accs = __builtin_amdgcn_mfma_f32_16x16x32_bf16(qv, bfr, accs, 0, 0, 0);
      }
    }

    // ---- softmax over the 64 k of this split
    const int kq = w * 16 + ln;
    bool valid = tk_r[(size_t)b * NK + sp * KC + kq] >= 0;
    float sv[4], mx[4];
    #pragma unroll
    for (int q = 0; q < 4; ++q) {
      sv[q] = valid ? accs[q] * SCALE : -INFINITY;
      mx[q] = sv[q];
    }
    #pragma unroll
    for (int off = 1; off < 16; off <<= 1)
      #pragma unroll
      for (int q = 0; q < 4; ++q) mx[q] = fmaxf(mx[q], __shfl_xor(mx[q], off));
    if (ln == 0) {
      #pragma unroll
      for (int q = 0; q < 4; ++q) mlds[w * NH + lg * 4 + q] = mx[q];
    }
    __syncthreads();

    float pr[4], sm[4];
    #pragma unroll
    for (int q = 0; q < 4; ++q) {
      int h = lg * 4 + q;
      float m = fmaxf(fmaxf(mlds[h], mlds[NH + h]),
                      fmaxf(mlds[2 * NH + h], mlds[3 * NH + h]));
      m = fmaxf(m, -1e30f);
      pr[q] = __expf(sv[q] - m);
      sm[q] = pr[q];
    }
    #pragma unroll
    for (int off = 1; off < 16; off <<= 1)
      #pragma unroll
      for (int q = 0; q < 4; ++q) sm[q] += __shfl_xor(sm[q], off);
    if (ln == 0) {
      #pragma unroll
      for (int q = 0; q < 4; ++q) slds[w * NH + lg * 4 + q] = sm[q];
    }
    #pragma unroll
    for (int q = 0; q < 4; ++q)
      plds[(lg * 4 + q) * 72 + kq] = bf16c(pr[q]);
    __syncthreads();

    if (t < NH) {
      float m = fmaxf(fmaxf(mlds[t], mlds[NH + t]),
                      fmaxf(mlds[2 * NH + t], mlds[3 * NH + t]));
      m = fmaxf(m, -1e30f);
      float s = slds[t] + slds[NH + t] + slds[2 * NH + t] + slds[3 * NH + t];
      pm[((size_t)b * NSPLIT + sp) * NH + t] = m;
      psum[((size_t)b * NSPLIT + sp) * NH + t] = s;
    }

    // ---- PV
    f32x4 acco[8];
    #pragma unroll
    for (int nt = 0; nt < 8; ++nt) acco[nt] = {0.f, 0.f, 0.f, 0.f};

    #pragma unroll
    for (int ks = 0; ks < 2; ++ks) {
      sh8 pa = *(const sh8*)&plds[ln * 72 + ks * 32 + lg * 8];
      int kb = ks * 32 + lg * 8;
      #pragma unroll
      for (int nt = 0; nt < 8; ++nt) {
        int l0 = w * 128 + nt * 16;
        int s = (kb >> 2) * NSUB_D + (l0 >> 4);
        const short* base = &kvs[s * 64 + ln];
        sh8 bv;
        #pragma unroll
        for (int j = 0; j < 4; ++j) bv[j] = base[j * 16];
        #pragma unroll
        for (int j = 0; j < 4; ++j) bv[4 + j] = base[NSUB_D * 64 + j * 16];
        acco[nt] = __builtin_amdgcn_mfma_f32_16x16x32_bf16(pa, bv, acco[nt], 0, 0, 0);
      }
    }

    // ---- write po partial bf16 [b][sp][h][l]
    unsigned short* dst = po + (((size_t)b * NSPLIT + sp) * NH) * NL;
    #pragma unroll
    for (int nt = 0; nt < 8; ++nt) {
      int l = w * 128 + nt * 16 + ln;
      #pragma unroll
      for (int q = 0; q < 4; ++q)
        dst[(size_t)(lg * 4 + q) * NL + l] = (unsigned short)bf16c(acco[nt][q]);
    }
    __syncthreads();
  }
}

// ---------------- Kernel 3: combine + W_UV -> ov — DIAGNOSTIC REP_C x
__global__ __launch_bounds__(256)
void k_combine(const float* __restrict__ pm,
               const float* __restrict__ psum,
               const unsigned short* __restrict__ po,
               const float* __restrict__ wuv,
               float* __restrict__ ov) {
  int bh = blockIdx.x;
  int b = bh >> 4, h = bh & 15;
  __shared__ float clds[NSPLIT];
  __shared__ float ol[NL];
  __shared__ float red[2][NDV];
  int t = threadIdx.x;

  for (int rep = 0; rep < REP_C; ++rep) {
    int zero;
    asm volatile("v_mov_b32 %0, 0" : "=v"(zero));
    const float* pm_r = pm + zero;
    const float* ps_r = psum + zero;
    const unsigned short* po_r = po + zero;
    const float* wuv_r = wuv + zero;

    if (t < NSPLIT) {
      float m = pm_r[((size_t)b * NSPLIT + t) * NH + h];
      float M = m;
      #pragma unroll
      for (int off = 16; off; off >>= 1) M = fmaxf(M, __shfl_xor(M, off, 32));
      float term = ps_r[((size_t)b * NSPLIT + t) * NH + h] * __expf(m - M);
      float S = term;
      #pragma unroll
      for (int off = 16; off; off >>= 1) S += __shfl_xor(S, off, 32);
      clds[t] = __expf(m - M) / fmaxf(S, 1e-30f);
    }
    __syncthreads();
    {
      float a0 = 0.f, a1 = 0.f;
      #pragma unroll
      for (int i = 0; i < NSPLIT; ++i) {
        uint32_t pv = *(const uint32_t*)&po_r[(((size_t)b * NSPLIT + i) * NH + h) * NL + 2 * t];
        a0 += clds[i] * bf2f((short)(pv & 0xffff));
        a1 += clds[i] * bf2f((short)(pv >> 16));
      }
      ol[2 * t] = a0;
      ol[2 * t + 1] = a1;
    }
    __syncthreads();
    {
      int v = t & (NDV - 1);
      int half = t >> 7;
      float a = 0.f;
      #pragma unroll 16
      for (int l = half * 256; l < half * 256 + 256; ++l)
        a += ol[l] * wuv_r[((size_t)l * NH + h) * NDV + v];
      red[half][v] = a;
    }
    __syncthreads();
    if (t < NDV) ov[(size_t)bh * NDV + t] = red[0][t] + red[1][t];
    __syncthreads();
  }
}

// ---------------- Kernel 4: GEMM over k-chunks of 32, atomic accumulate to out
__global__ __launch_bounds__(256)
void k_gemm_atomic(const float* __restrict__ ov,
                   const float* __restrict__ wo,
                   float* __restrict__ out) {
  int mc = blockIdx.x;  // 0..7
  int ns = blockIdx.y;  // 0..NS2-1
  __shared__ float oc[NB * 32];
  int t = threadIdx.x;
  for (int i = t; i < NB * 32; i += 256) {
    int b = i >> 5, n = i & 31;
    oc[i] = ov[(size_t)b * NDM + ns * 32 + n];
  }
  __syncthreads();
  float acc[NB];
  #pragma unroll
  for (int b = 0; b < NB; ++b) acc[b] = 0.f;
  int m = mc * 256 + t;
  #pragma unroll 8
  for (int n = 0; n < 32; ++n) {
    float wv = wo[(size_t)(ns * 32 + n) * NDM + m];
    #pragma unroll
    for (int b = 0; b < NB; ++b) acc[b] += oc[b * 32 + n] * wv;
  }
  #pragma unroll
  for (int b = 0; b < NB; ++b)
    atomicAdd(&out[(size_t)b * NDM + m], acc[b]);
}

extern "C" void kernel_launch(void* const* d_in, const int* in_sizes, int n_in,
                              void* d_out, int out_size, void* d_ws, size_t ws_size,
                              hipStream_t stream) {
  const float* q_nope = (const float*)d_in[0];
  const float* q_pe   = (const float*)d_in[1];
  const float* kv_c   = (const float*)d_in[2];
  const float* k_pe   = (const float*)d_in[3];
  const float* W_UK   = (const float*)d_in[4];
  const float* W_UV   = (const float*)d_in[5];
  const float* W_O    = (const float*)d_in[6];
  const int*   topk   = (const int*)d_in[7];
  float* out = (float*)d_out;

  float* ws = (float*)d_ws;
  short* qle = (short*)ws;                               // NB*NH*576 bf16 (147456 floats reserved)
  float* pm   = ws + 147456;                             // NB*NSPLIT*NH = 16384
  float* psum = pm + 16384;                              // 16384
  unsigned short* po = (unsigned short*)(psum + 16384);  // NB*NSPLIT*NH*NL bf16 (4194304 floats)
  float* ov   = psum + 16384 + 4194304;                  // NB*NH*NDV = 65536

  hipMemsetAsync(d_out, 0, (size_t)out_size * sizeof(float), stream);
  k_qprep<<<256, 256, 0, stream>>>(q_nope, q_pe, W_UK, qle);
  k_attn<<<dim3(NSPLIT, NB), 256, 0, stream>>>(kv_c, k_pe, topk, qle,
                                               pm, psum, po);
  k_combine<<<NB * NH, 256, 0, stream>>>(pm, psum, po, W_UV, ov);
  k_gemm_atomic<<<dim3(8, NS2), 256, 0, stream>>>(ov, W_O, out);
}

// Round 14
// 87.179 us; speedup vs baseline: 12.5481x; 12.5481x over previous
//
#include <hip/hip_runtime.h>
#include <hip/hip_bf16.h>
#include <cstdint>
#include <cstddef>

// Problem constants
constexpr int NB = 32;     // batch
constexpr int NH = 16;     // heads
constexpr int NS = 8192;   // seq len
constexpr int NK = 2048;   // top-k
constexpr int NL = 512;    // latent dim
constexpr int NDR = 64;    // rope dim
constexpr int NDV = 128;   // v head dim
constexpr int NDM = 2048;  // model dim
constexpr int NDN = 128;   // nope dim
constexpr float SCALE = 0.07216878364870322f; // 1/sqrt(192)

constexpr int NSPLIT = 64;      // k-splits (KC=32 => 4 blocks/CU in attn)
constexpr int KC = NK / NSPLIT; // 32 k per block
constexpr int ND = NL + NDR;    // 576 staged dims
constexpr int NSUB_D = ND / 16; // 36 subtiles per 4-row group
constexpr int NS2 = 64;         // k-chunks for final GEMM (32 n each)

typedef __attribute__((ext_vector_type(8))) short sh8;
typedef __attribute__((ext_vector_type(4))) float f32x4;

__device__ __forceinline__ short bf16c(float f) {
  union { float f; uint32_t u; } v; v.f = f;
  uint32_t r = v.u + 0x7fffu + ((v.u >> 16) & 1u);
  return (short)(r >> 16);
}

__device__ __forceinline__ float bf2f(short s) {
  union { uint32_t u; float f; } v; v.u = ((uint32_t)(uint16_t)s) << 16;
  return v.f;
}

__device__ __forceinline__ sh8 pack_bf8(float4 a, float4 b) {
  sh8 f;
  f[0] = bf16c(a.x); f[1] = bf16c(a.y); f[2] = bf16c(a.z); f[3] = bf16c(a.w);
  f[4] = bf16c(b.x); f[5] = bf16c(b.y); f[6] = bf16c(b.z); f[7] = bf16c(b.w);
  return f;
}

// ---------------- Kernel 1: qle via LDS-staged coalesced tiles; also zeroes out
__global__ __launch_bounds__(256)
void k_qprep(const float* __restrict__ qn,
             const float* __restrict__ qpe,
             const float* __restrict__ wuk,
             short* __restrict__ qle,
             float* __restrict__ out) {
  const int h  = blockIdx.x & 15;
  const int lc = blockIdx.x >> 4;
  const int l0 = lc * 32;
  const int t  = threadIdx.x;
  __shared__ float wlds[32 * 136];
  __shared__ float qlds[32 * 136];

  out[(size_t)blockIdx.x * 256 + t] = 0.f;   // 256*256 = NB*NDM

  #pragma unroll
  for (int j = 0; j < 4; ++j) {
    int idx = t + j * 256;
    int li  = idx >> 5;
    int d4  = (idx & 31) * 4;
    *(float4*)&wlds[li * 136 + d4] =
        *(const float4*)&wuk[((size_t)(l0 + li) * NH + h) * NDN + d4];
    *(float4*)&qlds[li * 136 + d4] =
        *(const float4*)&qn[((size_t)li * NH + h) * NDN + d4];
  }
  __syncthreads();

  const int b = t >> 3;
  #pragma unroll
  for (int j = 0; j < 4; ++j) {
    int li = (t & 7) + j * 8;
    float acc = 0.f;
    #pragma unroll
    for (int d4 = 0; d4 < NDN; d4 += 4) {
      float4 wv = *(float4*)&wlds[li * 136 + d4];
      float4 qv = *(float4*)&qlds[b * 136 + d4];
      acc += wv.x * qv.x + wv.y * qv.y + wv.z * qv.z + wv.w * qv.w;
    }
    qle[((size_t)b * NH + h) * ND + l0 + li] = bf16c(acc);
  }
  if (lc == 0) {
    #pragma unroll
    for (int j = 0; j < 8; ++j) {
      int i = t + j * 256;
      int bb = i >> 6, dr = i & 63;
      qle[((size_t)bb * NH + h) * ND + NL + dr] =
          bf16c(qpe[((size_t)bb * NH + h) * NDR + dr]);
    }
  }
}

// ---------------- Kernel 2: MFMA flash attention partial per (split, b)
// KC=32, LDS ~38.4KB -> 4 blocks/CU; staging issues all 18 loads before packing.
__global__ __launch_bounds__(256, 4)
void k_attn(const float* __restrict__ kvc,
            const float* __restrict__ kpe,
            const int*   __restrict__ topk,
            const short* __restrict__ qle,
            float* __restrict__ pm,
            float* __restrict__ psum,
            unsigned short* __restrict__ po) {
  const int sp = blockIdx.x;     // 0..NSPLIT-1
  const int b  = blockIdx.y;     // 0..NB-1
  const int t  = threadIdx.x;
  const int w  = t >> 6;         // wave 0..3
  const int lane = t & 63;
  const int lg = lane >> 4;      // lane group 0..3
  const int ln = lane & 15;

  __shared__ __align__(16) short kvs[(KC / 4) * NSUB_D * 64];   // 36864 B
  __shared__ __align__(16) short plds[NH * 40];                 // P bf16, row stride 40
  __shared__ float mlds[2 * NH];
  __shared__ float slds[2 * NH];

  // ---- gather-stage kv tile (32 rows x 576): all 18 float4 loads in flight
  {
    const int r = t >> 3, c8 = t & 7;   // 8 threads per row, 9 x 32B chunks each
    int idx = topk[(size_t)b * NK + sp * KC + r];
    int id = idx < 0 ? 0 : (idx >= NS ? NS - 1 : idx);
    const float* rowc = kvc + ((size_t)b * NS + id) * NL;
    const float* rowp = kpe + ((size_t)b * NS + id) * NDR;
    float4 va[9], vb[9];
    #pragma unroll
    for (int i = 0; i < 9; ++i) {
      int d0 = c8 * 8 + i * 64;
      const float* src = (d0 < NL) ? (rowc + d0) : (rowp + (d0 - NL));
      va[i] = *(const float4*)src;
      vb[i] = *(const float4*)(src + 4);
    }
    #pragma unroll
    for (int i = 0; i < 9; ++i) {
      int d0 = c8 * 8 + i * 64;
      int s = (r >> 2) * NSUB_D + (d0 >> 4);
      *(sh8*)&kvs[s * 64 + (r & 3) * 16 + (d0 & 15)] = pack_bf8(va[i], vb[i]);
    }
  }
  __syncthreads();

  // ---- QK^T: waves 0-1, wave w owns k-tile [w*16, w*16+16)
  float sv[4];
  if (w < 2) {
    f32x4 accs = {0.f, 0.f, 0.f, 0.f};
    const short* qrow = qle + ((size_t)b * NH + ln) * ND;
    int k = w * 16 + ln;
    int kbase = (k >> 2) * NSUB_D * 64 + (k & 3) * 16;
    #pragma unroll
    for (int kk = 0; kk < 18; ++kk) {
      int d0 = kk * 32 + lg * 8;
      sh8 qv = *(const sh8*)&qrow[d0];
      sh8 bfr = *(const sh8*)&kvs[kbase + (d0 >> 4) * 64 + (d0 & 15)];
      accs = __builtin_amdgcn_mfma_f32_16x16x32_bf16(qv, bfr, accs, 0, 0, 0);
    }
    const int kq = w * 16 + ln;
    bool valid = topk[(size_t)b * NK + sp * KC + kq] >= 0;
    float mx[4];
    #pragma unroll
    for (int q = 0; q < 4; ++q) {
      sv[q] = valid ? accs[q] * SCALE : -INFINITY;
      mx[q] = sv[q];
    }
    #pragma unroll
    for (int off = 1; off < 16; off <<= 1)
      #pragma unroll
      for (int q = 0; q < 4; ++q) mx[q] = fmaxf(mx[q], __shfl_xor(mx[q], off));
    if (ln == 0) {
      #pragma unroll
      for (int q = 0; q < 4; ++q) mlds[w * NH + lg * 4 + q] = mx[q];
    }
  }
  __syncthreads();

  if (w < 2) {
    const int kq = w * 16 + ln;
    float pr[4], sm[4];
    #pragma unroll
    for (int q = 0; q < 4; ++q) {
      int h = lg * 4 + q;
      float m = fmaxf(fmaxf(mlds[h], mlds[NH + h]), -1e30f);
      pr[q] = __expf(sv[q] - m);
      sm[q] = pr[q];
    }
    #pragma unroll
    for (int off = 1; off < 16; off <<= 1)
      #pragma unroll
      for (int q = 0; q < 4; ++q) sm[q] += __shfl_xor(sm[q], off);
    if (ln == 0) {
      #pragma unroll
      for (int q = 0; q < 4; ++q) slds[w * NH + lg * 4 + q] = sm[q];
    }
    #pragma unroll
    for (int q = 0; q < 4; ++q)
      plds[(lg * 4 + q) * 40 + kq] = bf16c(pr[q]);
  }
  __syncthreads();

  if (t < NH) {
    float m = fmaxf(fmaxf(mlds[t], mlds[NH + t]), -1e30f);
    float s = slds[t] + slds[NH + t];
    pm[((size_t)b * NSPLIT + sp) * NH + t] = m;
    psum[((size_t)b * NSPLIT + sp) * NH + t] = s;
  }

  // ---- PV: O[h][l] partial; wave w owns l-range [w*128, w*128+128); single k-pass
  f32x4 acco[8];
  #pragma unroll
  for (int nt = 0; nt < 8; ++nt) acco[nt] = {0.f, 0.f, 0.f, 0.f};
  {
    sh8 pa = *(const sh8*)&plds[ln * 40 + lg * 8];  // P[h=ln][k=lg*8+j]
    #pragma unroll
    for (int nt = 0; nt < 8; ++nt) {
      int l0 = w * 128 + nt * 16;
      const short* base = &kvs[(lg * 2) * NSUB_D * 64 + (l0 >> 4) * 64 + ln];
      sh8 bv;
      #pragma unroll
      for (int j = 0; j < 4; ++j) bv[j] = base[j * 16];
      #pragma unroll
      for (int j = 0; j < 4; ++j) bv[4 + j] = base[NSUB_D * 64 + j * 16];
      acco[nt] = __builtin_amdgcn_mfma_f32_16x16x32_bf16(pa, bv, acco[nt], 0, 0, 0);
    }
  }

  // ---- write po partial bf16 [b][sp][h][l]
  unsigned short* dst = po + (((size_t)b * NSPLIT + sp) * NH) * NL;
  #pragma unroll
  for (int nt = 0; nt < 8; ++nt) {
    int l = w * 128 + nt * 16 + ln;
    #pragma unroll
    for (int q = 0; q < 4; ++q)
      dst[(size_t)(lg * 4 + q) * NL + l] = (unsigned short)bf16c(acco[nt][q]);
  }
}

// ---------------- Kernel 3: combine splits (coef inline) + W_UV -> ov[b, h*DV + v]
__global__ __launch_bounds__(256)
void k_combine(const float* __restrict__ pm,
               const float* __restrict__ psum,
               const unsigned short* __restrict__ po,
               const float* __restrict__ wuv,
               float* __restrict__ ov) {
  int bh = blockIdx.x;
  int b = bh >> 4, h = bh & 15;
  __shared__ float clds[NSPLIT];
  __shared__ float ol[NL];
  __shared__ float red[2][NDV];
  int t = threadIdx.x;
  if (t < NSPLIT) {   // 64 lanes = wave 0, width-64 shuffles
    float m = pm[((size_t)b * NSPLIT + t) * NH + h];
    float M = m;
    #pragma unroll
    for (int off = 32; off; off >>= 1) M = fmaxf(M, __shfl_xor(M, off));
    float term = psum[((size_t)b * NSPLIT + t) * NH + h] * __expf(m - M);
    float S = term;
    #pragma unroll
    for (int off = 32; off; off >>= 1) S += __shfl_xor(S, off);
    clds[t] = __expf(m - M) / fmaxf(S, 1e-30f);
  }
  __syncthreads();
  {
    float a0 = 0.f, a1 = 0.f;
    #pragma unroll
    for (int i = 0; i < NSPLIT; ++i) {
      uint32_t pv = *(const uint32_t*)&po[(((size_t)b * NSPLIT + i) * NH + h) * NL + 2 * t];
      a0 += clds[i] * bf2f((short)(pv & 0xffff));
      a1 += clds[i] * bf2f((short)(pv >> 16));
    }
    ol[2 * t] = a0;
    ol[2 * t + 1] = a1;
  }
  __syncthreads();
  {
    int v = t & (NDV - 1);
    int half = t >> 7;
    float a = 0.f;
    #pragma unroll 16
    for (int l = half * 256; l < half * 256 + 256; ++l)
      a += ol[l] * wuv[((size_t)l * NH + h) * NDV + v];
    red[half][v] = a;
  }
  __syncthreads();
  if (t < NDV) ov[(size_t)bh * NDV + t] = red[0][t] + red[1][t];
}

// ---------------- Kernel 4: GEMM over k-chunks of 32, atomic accumulate to out
__global__ __launch_bounds__(256)
void k_gemm_atomic(const float* __restrict__ ov,
                   const float* __restrict__ wo,
                   float* __restrict__ out) {
  int mc = blockIdx.x;  // 0..7
  int ns = blockIdx.y;  // 0..NS2-1
  __shared__ float oc[NB * 32];
  int t = threadIdx.x;
  for (int i = t; i < NB * 32; i += 256) {
    int b = i >> 5, n = i & 31;
    oc[i] = ov[(size_t)b * NDM + ns * 32 + n];
  }
  __syncthreads();
  float acc[NB];
  #pragma unroll
  for (int b = 0; b < NB; ++b) acc[b] = 0.f;
  int m = mc * 256 + t;
  #pragma unroll 8
  for (int n = 0; n < 32; ++n) {
    float wv = wo[(size_t)(ns * 32 + n) * NDM + m];
    #pragma unroll
    for (int b = 0; b < NB; ++b) acc[b] += oc[b * 32 + n] * wv;
  }
  #pragma unroll
  for (int b = 0; b < NB; ++b)
    atomicAdd(&out[(size_t)b * NDM + m], acc[b]);
}

extern "C" void kernel_launch(void* const* d_in, const int* in_sizes, int n_in,
                              void* d_out, int out_size, void* d_ws, size_t ws_size,
                              hipStream_t stream) {
  const float* q_nope = (const float*)d_in[0];
  const float* q_pe   = (const float*)d_in[1];
  const float* kv_c   = (const float*)d_in[2];
  const float* k_pe   = (const float*)d_in[3];
  const float* W_UK   = (const float*)d_in[4];
  const float* W_UV   = (const float*)d_in[5];
  const float* W_O    = (const float*)d_in[6];
  const int*   topk   = (const int*)d_in[7];
  float* out = (float*)d_out;

  float* ws = (float*)d_ws;
  short* qle = (short*)ws;                               // NB*NH*576 bf16 (147456 float slots)
  float* pm   = ws + 147456;                             // NB*NSPLIT*NH = 32768
  float* psum = pm + 32768;                              // 32768
  unsigned short* po = (unsigned short*)(psum + 32768);  // NB*NSPLIT*NH*NL bf16 (8388608 float slots)
  float* ov   = psum + 32768 + 8388608;                  // NB*NH*NDV = 65536

  k_qprep<<<256, 256, 0, stream>>>(q_nope, q_pe, W_UK, qle, out);
  k_attn<<<dim3(NSPLIT, NB), 256, 0, stream>>>(kv_c, k_pe, topk, qle,
                                               pm, psum, po);
  k_combine<<<NB * NH, 256, 0, stream>>>(pm, psum, po, W_UV, ov);
  k_gemm_atomic<<<dim3(8, NS2), 256, 0, stream>>>(ov, W_O, out);
}

// Round 15
// 86.164 us; speedup vs baseline: 12.6959x; 1.0118x over previous
//
#include <hip/hip_runtime.h>
#include <hip/hip_bf16.h>
#include <cstdint>
#include <cstddef>

// Problem constants
constexpr int NB = 32;     // batch
constexpr int NH = 16;     // heads
constexpr int NS = 8192;   // seq len
constexpr int NK = 2048;   // top-k
constexpr int NL = 512;    // latent dim
constexpr int NDR = 64;    // rope dim
constexpr int NDV = 128;   // v head dim
constexpr int NDM = 2048;  // model dim
constexpr int NDN = 128;   // nope dim
constexpr float SCALE = 0.07216878364870322f; // 1/sqrt(192)

constexpr int NSPLIT = 64;      // k-splits (KC=32 => 4 blocks/CU in attn)
constexpr int KC = NK / NSPLIT; // 32 k per block
constexpr int ND = NL + NDR;    // 576 staged dims
constexpr int NSUB_D = ND / 16; // 36 subtiles per 4-row group
constexpr int NS2 = 64;         // k-chunks for final GEMM (32 n each)

typedef __attribute__((ext_vector_type(8))) short sh8;
typedef __attribute__((ext_vector_type(4))) float f32x4;

// RNE float->bf16 via HIP intrinsic: pairs fuse into v_cvt_pk_bf16_f32 (m240)
__device__ __forceinline__ short bf16c(float f) {
  __hip_bfloat16 h = __float2bfloat16(f);
  return *(short*)&h;
}

__device__ __forceinline__ float bf2f(short s) {
  union { uint32_t u; float f; } v; v.u = ((uint32_t)(uint16_t)s) << 16;
  return v.f;
}

__device__ __forceinline__ sh8 pack_bf8(float4 a, float4 b) {
  sh8 f;
  f[0] = bf16c(a.x); f[1] = bf16c(a.y); f[2] = bf16c(a.z); f[3] = bf16c(a.w);
  f[4] = bf16c(b.x); f[5] = bf16c(b.y); f[6] = bf16c(b.z); f[7] = bf16c(b.w);
  return f;
}

// ---------------- Kernel 1: qle via LDS-staged coalesced tiles; also zeroes out
__global__ __launch_bounds__(256)
void k_qprep(const float* __restrict__ qn,
             const float* __restrict__ qpe,
             const float* __restrict__ wuk,
             short* __restrict__ qle,
             float* __restrict__ out) {
  const int h  = blockIdx.x & 15;
  const int lc = blockIdx.x >> 4;
  const int l0 = lc * 32;
  const int t  = threadIdx.x;
  __shared__ float wlds[32 * 136];
  __shared__ float qlds[32 * 136];

  out[(size_t)blockIdx.x * 256 + t] = 0.f;   // 256*256 = NB*NDM

  #pragma unroll
  for (int j = 0; j < 4; ++j) {
    int idx = t + j * 256;
    int li  = idx >> 5;
    int d4  = (idx & 31) * 4;
    *(float4*)&wlds[li * 136 + d4] =
        *(const float4*)&wuk[((size_t)(l0 + li) * NH + h) * NDN + d4];
    *(float4*)&qlds[li * 136 + d4] =
        *(const float4*)&qn[((size_t)li * NH + h) * NDN + d4];
  }
  __syncthreads();

  const int b = t >> 3;
  #pragma unroll
  for (int j = 0; j < 4; ++j) {
    int li = (t & 7) + j * 8;
    float acc = 0.f;
    #pragma unroll
    for (int d4 = 0; d4 < NDN; d4 += 4) {
      float4 wv = *(float4*)&wlds[li * 136 + d4];
      float4 qv = *(float4*)&qlds[b * 136 + d4];
      acc += wv.x * qv.x + wv.y * qv.y + wv.z * qv.z + wv.w * qv.w;
    }
    qle[((size_t)b * NH + h) * ND + l0 + li] = bf16c(acc);
  }
  if (lc == 0) {
    #pragma unroll
    for (int j = 0; j < 8; ++j) {
      int i = t + j * 256;
      int bb = i >> 6, dr = i & 63;
      qle[((size_t)bb * NH + h) * ND + NL + dr] =
          bf16c(qpe[((size_t)bb * NH + h) * NDR + dr]);
    }
  }
}

// ---------------- Kernel 2: MFMA flash attention partial; XCD-swizzled 1D grid
__global__ __launch_bounds__(256, 4)
void k_attn(const float* __restrict__ kvc,
            const float* __restrict__ kpe,
            const int*   __restrict__ topk,
            const short* __restrict__ qle,
            float* __restrict__ pm,
            float* __restrict__ psum,
            unsigned short* __restrict__ po) {
  // bijective XCD swizzle: 2048 blocks, 8 XCDs, 256 per XCD.
  // consecutive swz on one XCD => each XCD works 4 consecutive batches.
  const int bid = blockIdx.x;
  const int swz = (bid & 7) * 256 + (bid >> 3);
  const int sp = swz & (NSPLIT - 1);   // 0..63
  const int b  = swz >> 6;             // 0..31
  const int t  = threadIdx.x;
  const int w  = t >> 6;               // wave 0..3
  const int lane = t & 63;
  const int lg = lane >> 4;            // lane group 0..3
  const int ln = lane & 15;

  __shared__ __align__(16) short kvs[(KC / 4) * NSUB_D * 64];   // 36864 B
  __shared__ __align__(16) short plds[NH * 40];                 // P bf16, row stride 40
  __shared__ float mlds[2 * NH];
  __shared__ float slds[2 * NH];

  // ---- gather-stage kv tile (32 rows x 576): all 18 float4 loads in flight
  {
    const int r = t >> 3, c8 = t & 7;   // 8 threads per row, 9 x 32B chunks each
    int idx = topk[(size_t)b * NK + sp * KC + r];
    int id = idx < 0 ? 0 : (idx >= NS ? NS - 1 : idx);
    const float* rowc = kvc + ((size_t)b * NS + id) * NL;
    const float* rowp = kpe + ((size_t)b * NS + id) * NDR;
    float4 va[9], vb[9];
    #pragma unroll
    for (int i = 0; i < 9; ++i) {
      int d0 = c8 * 8 + i * 64;
      const float* src = (d0 < NL) ? (rowc + d0) : (rowp + (d0 - NL));
      va[i] = *(const float4*)src;
      vb[i] = *(const float4*)(src + 4);
    }
    #pragma unroll
    for (int i = 0; i < 9; ++i) {
      int d0 = c8 * 8 + i * 64;
      int s = (r >> 2) * NSUB_D + (d0 >> 4);
      *(sh8*)&kvs[s * 64 + (r & 3) * 16 + (d0 & 15)] = pack_bf8(va[i], vb[i]);
    }
  }
  __syncthreads();

  // ---- QK^T: waves 0-1, wave w owns k-tile [w*16, w*16+16)
  float sv[4];
  if (w < 2) {
    f32x4 accs = {0.f, 0.f, 0.f, 0.f};
    const short* qrow = qle + ((size_t)b * NH + ln) * ND;
    int k = w * 16 + ln;
    int kbase = (k >> 2) * NSUB_D * 64 + (k & 3) * 16;
    #pragma unroll
    for (int kk = 0; kk < 18; ++kk) {
      int d0 = kk * 32 + lg * 8;
      sh8 qv = *(const sh8*)&qrow[d0];
      sh8 bfr = *(const sh8*)&kvs[kbase + (d0 >> 4) * 64 + (d0 & 15)];
      accs = __builtin_amdgcn_mfma_f32_16x16x32_bf16(qv, bfr, accs, 0, 0, 0);
    }
    const int kq = w * 16 + ln;
    bool valid = topk[(size_t)b * NK + sp * KC + kq] >= 0;
    float mx[4];
    #pragma unroll
    for (int q = 0; q < 4; ++q) {
      sv[q] = valid ? accs[q] * SCALE : -INFINITY;
      mx[q] = sv[q];
    }
    #pragma unroll
    for (int off = 1; off < 16; off <<= 1)
      #pragma unroll
      for (int q = 0; q < 4; ++q) mx[q] = fmaxf(mx[q], __shfl_xor(mx[q], off));
    if (ln == 0) {
      #pragma unroll
      for (int q = 0; q < 4; ++q) mlds[w * NH + lg * 4 + q] = mx[q];
    }
  }
  __syncthreads();

  if (w < 2) {
    const int kq = w * 16 + ln;
    float pr[4], sm[4];
    #pragma unroll
    for (int q = 0; q < 4; ++q) {
      int h = lg * 4 + q;
      float m = fmaxf(fmaxf(mlds[h], mlds[NH + h]), -1e30f);
      pr[q] = __expf(sv[q] - m);
      sm[q] = pr[q];
    }
    #pragma unroll
    for (int off = 1; off < 16; off <<= 1)
      #pragma unroll
      for (int q = 0; q < 4; ++q) sm[q] += __shfl_xor(sm[q], off);
    if (ln == 0) {
      #pragma unroll
      for (int q = 0; q < 4; ++q) slds[w * NH + lg * 4 + q] = sm[q];
    }
    #pragma unroll
    for (int q = 0; q < 4; ++q)
      plds[(lg * 4 + q) * 40 + kq] = bf16c(pr[q]);
  }
  __syncthreads();

  if (t < NH) {
    float m = fmaxf(fmaxf(mlds[t], mlds[NH + t]), -1e30f);
    float s = slds[t] + slds[NH + t];
    pm[((size_t)b * NSPLIT + sp) * NH + t] = m;
    psum[((size_t)b * NSPLIT + sp) * NH + t] = s;
  }

  // ---- PV: O[h][l] partial; wave w owns l-range [w*128, w*128+128); single k-pass
  f32x4 acco[8];
  #pragma unroll
  for (int nt = 0; nt < 8; ++nt) acco[nt] = {0.f, 0.f, 0.f, 0.f};
  {
    sh8 pa = *(const sh8*)&plds[ln * 40 + lg * 8];  // P[h=ln][k=lg*8+j]
    #pragma unroll
    for (int nt = 0; nt < 8; ++nt) {
      int l0 = w * 128 + nt * 16;
      const short* base = &kvs[(lg * 2) * NSUB_D * 64 + (l0 >> 4) * 64 + ln];
      sh8 bv;
      #pragma unroll
      for (int j = 0; j < 4; ++j) bv[j] = base[j * 16];
      #pragma unroll
      for (int j = 0; j < 4; ++j) bv[4 + j] = base[NSUB_D * 64 + j * 16];
      acco[nt] = __builtin_amdgcn_mfma_f32_16x16x32_bf16(pa, bv, acco[nt], 0, 0, 0);
    }
  }

  // ---- write po partial bf16 [b][sp][h][l]
  unsigned short* dst = po + (((size_t)b * NSPLIT + sp) * NH) * NL;
  #pragma unroll
  for (int nt = 0; nt < 8; ++nt) {
    int l = w * 128 + nt * 16 + ln;
    #pragma unroll
    for (int q = 0; q < 4; ++q)
      dst[(size_t)(lg * 4 + q) * NL + l] = (unsigned short)bf16c(acco[nt][q]);
  }
}

// ---------------- Kernel 3: combine splits (coef inline) + W_UV -> ov[b, h*DV + v]
__global__ __launch_bounds__(256)
void k_combine(const float* __restrict__ pm,
               const float* __restrict__ psum,
               const unsigned short* __restrict__ po,
               const float* __restrict__ wuv,
               float* __restrict__ ov) {
  int bh = blockIdx.x;
  int b = bh >> 4, h = bh & 15;
  __shared__ float clds[NSPLIT];
  __shared__ float ol[NL];
  __shared__ float red[2][NDV];
  int t = threadIdx.x;
  if (t < NSPLIT) {   // 64 lanes = wave 0, width-64 shuffles
    float m = pm[((size_t)b * NSPLIT + t) * NH + h];
    float M = m;
    #pragma unroll
    for (int off = 32; off; off >>= 1) M = fmaxf(M, __shfl_xor(M, off));
    float term = psum[((size_t)b * NSPLIT + t) * NH + h] * __expf(m - M);
    float S = term;
    #pragma unroll
    for (int off = 32; off; off >>= 1) S += __shfl_xor(S, off);
    clds[t] = __expf(m - M) / fmaxf(S, 1e-30f);
  }
  __syncthreads();
  {
    float a0 = 0.f, a1 = 0.f;
    #pragma unroll
    for (int i = 0; i < NSPLIT; ++i) {
      uint32_t pv = *(const uint32_t*)&po[(((size_t)b * NSPLIT + i) * NH + h) * NL + 2 * t];
      a0 += clds[i] * bf2f((short)(pv & 0xffff));
      a1 += clds[i] * bf2f((short)(pv >> 16));
    }
    ol[2 * t] = a0;
    ol[2 * t + 1] = a1;
  }
  __syncthreads();
  {
    int v = t & (NDV - 1);
    int half = t >> 7;
    float a = 0.f;
    #pragma unroll 16
    for (int l = half * 256; l < half * 256 + 256; ++l)
      a += ol[l] * wuv[((size_t)l * NH + h) * NDV + v];
    red[half][v] = a;
  }
  __syncthreads();
  if (t < NDV) ov[(size_t)bh * NDV + t] = red[0][t] + red[1][t];
}

// ---------------- Kernel 4: GEMM over k-chunks of 32, atomic accumulate to out
__global__ __launch_bounds__(256)
void k_gemm_atomic(const float* __restrict__ ov,
                   const float* __restrict__ wo,
                   float* __restrict__ out) {
  int mc = blockIdx.x;  // 0..7
  int ns = blockIdx.y;  // 0..NS2-1
  __shared__ float oc[NB * 32];
  int t = threadIdx.x;
  for (int i = t; i < NB * 32; i += 256) {
    int b = i >> 5, n = i & 31;
    oc[i] = ov[(size_t)b * NDM + ns * 32 + n];
  }
  __syncthreads();
  float acc[NB];
  #pragma unroll
  for (int b = 0; b < NB; ++b) acc[b] = 0.f;
  int m = mc * 256 + t;
  #pragma unroll 8
  for (int n = 0; n < 32; ++n) {
    float wv = wo[(size_t)(ns * 32 + n) * NDM + m];
    #pragma unroll
    for (int b = 0; b < NB; ++b) acc[b] += oc[b * 32 + n] * wv;
  }
  #pragma unroll
  for (int b = 0; b < NB; ++b)
    atomicAdd(&out[(size_t)b * NDM + m], acc[b]);
}

extern "C" void kernel_launch(void* const* d_in, const int* in_sizes, int n_in,
                              void* d_out, int out_size, void* d_ws, size_t ws_size,
                              hipStream_t stream) {
  const float* q_nope = (const float*)d_in[0];
  const float* q_pe   = (const float*)d_in[1];
  const float* kv_c   = (const float*)d_in[2];
  const float* k_pe   = (const float*)d_in[3];
  const float* W_UK   = (const float*)d_in[4];
  const float* W_UV   = (const float*)d_in[5];
  const float* W_O    = (const float*)d_in[6];
  const int*   topk   = (const int*)d_in[7];
  float* out = (float*)d_out;

  float* ws = (float*)d_ws;
  short* qle = (short*)ws;                               // NB*NH*576 bf16 (147456 float slots)
  float* pm   = ws + 147456;                             // NB*NSPLIT*NH = 32768
  float* psum = pm + 32768;                              // 32768
  unsigned short* po = (unsigned short*)(psum + 32768);  // NB*NSPLIT*NH*NL bf16 (8388608 float slots)
  float* ov   = psum + 32768 + 8388608;                  // NB*NH*NDV = 65536

  k_qprep<<<256, 256, 0, stream>>>(q_nope, q_pe, W_UK, qle, out);
  k_attn<<<NSPLIT * NB, 256, 0, stream>>>(kv_c, k_pe, topk, qle,
                                          pm, psum, po);
  k_combine<<<NB * NH, 256, 0, stream>>>(pm, psum, po, W_UV, ov);
  k_gemm_atomic<<<dim3(8, NS2), 256, 0, stream>>>(ov, W_O, out);
}